// Round 1
// baseline (255.145 us; speedup 1.0000x reference)
//
#include <hip/hip_runtime.h>
#include <stdint.h>

#define SEQ   2048
#define DIM   1024
#define BATCH 4

typedef _Float16 f16;
typedef __attribute__((ext_vector_type(8))) _Float16 f16x8;
typedef __attribute__((ext_vector_type(4))) _Float16 f16x4;
typedef __attribute__((ext_vector_type(4))) float   f32x4;

typedef void __attribute__((address_space(1))) vg_t;
typedef void __attribute__((address_space(3))) vl_t;

__device__ __forceinline__ void gld16(const void* g, void* l) {
  // async global->LDS, 16B per lane; LDS dest = wave-uniform base + lane*16
  __builtin_amdgcn_global_load_lds((vg_t*)g, (vl_t*)l, 16, 0, 0);
}

// ---------------------------------------------------------------------------
// Fused fp32->fp16 convert of x, Wq, Wk, Wv in ONE dispatch.
// blocks [0,8192): x (8M elems); [8192,9216): Wq; [9216,10240): Wk; rest: Wv.
// ---------------------------------------------------------------------------
__global__ __launch_bounds__(256) void cvt_all(const float* __restrict__ x,
                                               const float* __restrict__ wq,
                                               const float* __restrict__ wk,
                                               const float* __restrict__ wv,
                                               f16* __restrict__ xb,
                                               f16* __restrict__ wh) {
  const int bx = blockIdx.x;
  const float* in; f16* out; int base;
  if (bx < 8192)       { in = x;  out = xb;             base = bx; }
  else if (bx < 9216)  { in = wq; out = wh;             base = bx - 8192; }
  else if (bx < 10240) { in = wk; out = wh + (1 << 20); base = bx - 9216; }
  else                 { in = wv; out = wh + (2 << 20); base = bx - 10240; }
  const long i = ((long)base * 256 + threadIdx.x) * 4;
  float4 v = *(const float4*)(in + i);
  f16x4 o = { (f16)v.x, (f16)v.y, (f16)v.z, (f16)v.w };
  *(f16x4*)(out + i) = o;
}

// ---------------------------------------------------------------------------
// NT GEMM: C[m,n] = sum_k A[m,k]*B[n,k], fp16 in, fp32 accumulate.
// 128x128 tile, 4 waves (2x2 of 64x64), 16x16x32 MFMA, BK template (64/128).
// MODE: 0 = fp32 row-major C
//       1 = fp16 row-major C
//       2 = fp16 transposed C (C[n][m])
//       3 = fused QKV epilogue: col<1024 -> Q row-major, <2048 -> K row-major,
//           else -> V transposed [p][B*S] (Cv = Qh base; Kh/VT at fixed offsets)
// CAUSAL: 0 none, 1 skip tiles fully above diagonal (scores), 2 K-limit m0+128 (PV)
//         3 = PV with balanced 1D grid (512 blocks): anti-symmetric longest<->
//             shortest pairing so each CU's 2 resident blocks sum to ~const Keff.
//             (grid (16,8,4) with 2 slots/CU is fully resident at t=0 -> no
//              dynamic balancing; a CU with two Keff=2048 blocks is the 2x tail.)
// XOR chunk swizzle: LDS slot (row, j) holds global 16B chunk j ^ (row & (CH-1)).
// BK=64 everywhere: 32 KiB LDS -> ~5 blocks/CU. BK=128 (64 KiB, 2 blocks/CU)
// measured 508 vs 874 TF on this structure (m132) -- occupancy loss dominates.
// ---------------------------------------------------------------------------
template <int MODE, int CAUSAL, int BK>
__global__ __launch_bounds__(256) void gemm_bt(const f16* __restrict__ A, int lda, long aOffZ,
                                               const f16* __restrict__ B, int ldb, long bOffZ,
                                               void* __restrict__ Cv, int ldc, long cOffZ,
                                               int K) {
  constexpr int CH  = BK / 8;    // 16B chunks per row
  constexpr int RPL = 64 / CH;   // rows per wave-load (8 @BK64, 4 @BK128)
  constexpr int NL  = 32 / RPL;  // wave-loads per tile per wave (4 / 8)
  __shared__ __align__(16) f16 lA[128 * BK];
  __shared__ __align__(16) f16 lB[128 * BK];

  const int tid  = threadIdx.x;
  const int wave = tid >> 6;
  const int lane = tid & 63;

  int m0, n0, z;
  if (CAUSAL == 3) {
    // 512 work items, ranks sorted by descending Keff (m-tile 15 first).
    // id<256 walks ranks descending; id>=256 walks them ascending, so under
    // breadth-first round-robin dispatch CU c holds {rank c, rank 511-c}:
    // Keff sum == 2176 for every CU (vs worst-case 4096 with grid-order).
    const int id   = blockIdx.x;
    const int item = (id < 256) ? id : 767 - id;
    const int mt   = 15 - (item >> 5);     // 32 blocks per Keff group
    const int j    = item & 31;
    m0 = mt * 128;
    n0 = (j & 7) * 128;
    z  = j >> 3;
  } else {
    m0 = blockIdx.x * 128;
    n0 = blockIdx.y * 128;
    z  = blockIdx.z;
  }

  if (CAUSAL == 1 && n0 >= m0 + 128) return;
  const int Keff = (CAUSAL >= 2) ? (m0 + 128) : K;

  const f16* Ab = A + (long)z * aOffZ + (long)m0 * lda;
  const f16* Bb = B + (long)z * bOffZ + (long)n0 * ldb;

  const int wm = (wave & 1) * 64;
  const int wn = (wave >> 1) * 64;

  f32x4 acc[4][4] = {};

  const int srow = lane / CH;
  const int sj   = lane % CH;
  const int fr   = lane & 15;
  const int fq   = lane >> 4;

  for (int kt = 0; kt < Keff; kt += BK) {
    __syncthreads();  // previous iteration's ds_reads done
#pragma unroll
    for (int j = 0; j < NL; ++j) {
      const int rgrp = j * 4 + wave;
      const int row  = rgrp * RPL + srow;
      const int gch  = sj ^ (row & (CH - 1));
      gld16(Ab + (long)row * lda + kt + gch * 8, (void*)(lA + rgrp * 512 + lane * 8));
      gld16(Bb + (long)row * ldb + kt + gch * 8, (void*)(lB + rgrp * 512 + lane * 8));
    }
    __syncthreads();  // vmcnt drained -> staging visible

#pragma unroll
    for (int kk = 0; kk < BK; kk += 32) {
      f16x8 af[4], bf[4];
#pragma unroll
      for (int i = 0; i < 4; ++i) {
        const int arow = wm + i * 16 + fr;
        const int ach  = (kk / 8 + fq) ^ (arow & (CH - 1));
        af[i] = *(const f16x8*)(lA + arow * BK + ach * 8);
        const int brow = wn + i * 16 + fr;
        const int bch  = (kk / 8 + fq) ^ (brow & (CH - 1));
        bf[i] = *(const f16x8*)(lB + brow * BK + bch * 8);
      }
#pragma unroll
      for (int mi = 0; mi < 4; ++mi)
#pragma unroll
        for (int ni = 0; ni < 4; ++ni)
          acc[mi][ni] = __builtin_amdgcn_mfma_f32_16x16x32_f16(af[mi], bf[ni], acc[mi][ni], 0, 0, 0);
    }
  }

  // Epilogue. C/D layout: col = lane&15, row = (lane>>4)*4 + reg
#pragma unroll
  for (int mi = 0; mi < 4; ++mi) {
    const int row = m0 + wm + mi * 16 + fq * 4;
#pragma unroll
    for (int ni = 0; ni < 4; ++ni) {
      const int col = n0 + wn + ni * 16 + fr;
      if constexpr (MODE == 0) {
        float* C = (float*)Cv + (long)z * cOffZ;
#pragma unroll
        for (int r = 0; r < 4; ++r) C[(long)(row + r) * ldc + col] = acc[mi][ni][r];
      } else if constexpr (MODE == 1) {
        f16* C = (f16*)Cv + (long)z * cOffZ;
#pragma unroll
        for (int r = 0; r < 4; ++r) C[(long)(row + r) * ldc + col] = (f16)acc[mi][ni][r];
      } else if constexpr (MODE == 2) {
        f16* C = (f16*)Cv + (long)z * cOffZ;
        f16x4 o = { (f16)acc[mi][ni][0], (f16)acc[mi][ni][1],
                    (f16)acc[mi][ni][2], (f16)acc[mi][ni][3] };
        *(f16x4*)(C + (long)col * ldc + row) = o;
      } else {  // MODE 3: fused QKV routing (wave-uniform: 128-tile never straddles 1024-boundaries)
        f16* Qh  = (f16*)Cv;
        f16* Kh  = Qh + (size_t)8 * 1024 * 1024;
        f16* VTb = Kh + (size_t)8 * 1024 * 1024;
        if (col < 1024) {
#pragma unroll
          for (int r = 0; r < 4; ++r) Qh[(long)(row + r) * DIM + col] = (f16)acc[mi][ni][r];
        } else if (col < 2048) {
#pragma unroll
          for (int r = 0; r < 4; ++r) Kh[(long)(row + r) * DIM + (col - 1024)] = (f16)acc[mi][ni][r];
        } else {
          f16x4 o = { (f16)acc[mi][ni][0], (f16)acc[mi][ni][1],
                      (f16)acc[mi][ni][2], (f16)acc[mi][ni][3] };
          *(f16x4*)(VTb + (long)(col - 2048) * (BATCH * SEQ) + row) = o;
        }
      }
    }
  }
}

// ---------------------------------------------------------------------------
// Causal softmax over f16 score rows, in-place (zero above diagonal).
// grid = (SEQ, BATCH), block = 256, 8 contiguous elems/thread (f16x8).
// Threads whose whole 8-chunk is above the diagonal skip the load (the data is
// masked to -inf anyway) -- saves ~half the 32 MB of reads. Writes stay full:
// PV consumes the zeros up to k < m0+128.
// ---------------------------------------------------------------------------
__global__ __launch_bounds__(256) void softmax_causal(f16* S) {
  const int q = blockIdx.x, b = blockIdx.y;
  f16* row = S + ((long)b * SEQ + q) * SEQ;
  const int tid = threadIdx.x;
  const int lane = tid & 63, wave = tid >> 6;
  const int nvalid = q + 1;

  f16x8 vv = {};
  if (tid * 8 < nvalid) vv = *(const f16x8*)(row + tid * 8);
  float v[8];
  float m = -3.0e38f;
#pragma unroll
  for (int i = 0; i < 8; ++i) {
    const int k = tid * 8 + i;
    v[i] = (k < nvalid) ? (float)vv[i] * 0.03125f : -3.0e38f;
    m = fmaxf(m, v[i]);
  }
#pragma unroll
  for (int off = 32; off; off >>= 1) m = fmaxf(m, __shfl_xor(m, off));
  __shared__ float redm[4], reds[4];
  if (lane == 0) redm[wave] = m;
  __syncthreads();  // all reads of `row` complete before this point
  m = fmaxf(fmaxf(redm[0], redm[1]), fmaxf(redm[2], redm[3]));

  float s = 0.f;
#pragma unroll
  for (int i = 0; i < 8; ++i) {
    const float p = (v[i] > -1.0e37f) ? __expf(v[i] - m) : 0.f;
    v[i] = p;
    s += p;
  }
#pragma unroll
  for (int off = 32; off; off >>= 1) s += __shfl_xor(s, off);
  if (lane == 0) reds[wave] = s;
  __syncthreads();
  s = reds[0] + reds[1] + reds[2] + reds[3];
  const float inv = 1.f / s;
  f16x8 o;
#pragma unroll
  for (int i = 0; i < 8; ++i) o[i] = (f16)(v[i] * inv);
  *(f16x8*)(row + tid * 8) = o;  // after barriers -> no overlap hazard
}

// ---------------------------------------------------------------------------
extern "C" void kernel_launch(void* const* d_in, const int* in_sizes, int n_in,
                              void* d_out, int out_size, void* d_ws, size_t ws_size,
                              hipStream_t stream) {
  const float* x  = (const float*)d_in[0];
  const float* Wq = (const float*)d_in[1];
  const float* Wk = (const float*)d_in[2];
  const float* Wv = (const float*)d_in[3];
  float* out = (float*)d_out;

  // ws layout (f16 elems): xb 8M | Wh 3M | Qh 8M | Kh 8M | VT 8M ([1024][8192]) |
  //                        Sc 16M f16 scores->probs in place (4 x 2048 x 2048)
  if (ws_size < (size_t)51 * 1024 * 1024 * 2) return;

  f16* xb = (f16*)d_ws;
  f16* Wh = xb + (size_t)8 * 1024 * 1024;
  f16* Qh = Wh + (size_t)3 * 1024 * 1024;
  f16* Kh = Qh + (size_t)8 * 1024 * 1024;
  f16* VT = Kh + (size_t)8 * 1024 * 1024;
  f16* Sc = VT + (size_t)8 * 1024 * 1024;

  const long QOFF = (long)SEQ * DIM;  // per-batch Q/K offset
  const long SOFF = (long)SEQ * SEQ;  // per-batch score offset (f16 elems)

  cvt_all<<<11264, 256, 0, stream>>>(x, Wq, Wk, Wv, xb, Wh);

  // Fused QKV: M=8192, N=3072 (Wq|Wk|Wv concatenated in Wh), K=1024.
  // Epilogue writes Qh/Kh row-major f16 and VT transposed; BK=64 keeps 5 blocks/CU.
  gemm_bt<3, 0, 64><<<dim3(64, 24, 1), 256, 0, stream>>>(xb, DIM, 0, Wh, DIM, 0, Qh, 0, 0, DIM);

  // scores = Q K^T (causal block-skip), f16 out, BK=64 (occupancy > barrier amortization)
  gemm_bt<1, 1, 64><<<dim3(16, 16, 4), 256, 0, stream>>>(Qh, DIM, QOFF, Kh, DIM, QOFF,
                                                         Sc, SEQ, SOFF, DIM);

  // causal softmax (scale 1/32), in-place f16 probs, zero above diagonal
  softmax_causal<<<dim3(SEQ, BATCH), 256, 0, stream>>>(Sc);

  // Z = P V  (A = probs f16 ld 2048; B = VT ld 8192; per-M-tile K-limit),
  // BK=64 + balanced 1D grid (longest<->shortest pairing kills the Keff tail)
  gemm_bt<0, 3, 64><<<dim3(512, 1, 1), 256, 0, stream>>>(Sc, SEQ, SOFF,
                                                         VT, BATCH * SEQ, SEQ,
                                                         out, DIM, (long)SEQ * DIM, SEQ);
}

// Round 2
// 237.375 us; speedup vs baseline: 1.0749x; 1.0749x over previous
//
#include <hip/hip_runtime.h>
#include <stdint.h>

#define SEQ   2048
#define DIM   1024
#define BATCH 4

typedef _Float16 f16;
typedef __attribute__((ext_vector_type(8))) _Float16 f16x8;
typedef __attribute__((ext_vector_type(4))) _Float16 f16x4;
typedef __attribute__((ext_vector_type(4))) float   f32x4;

typedef void __attribute__((address_space(1))) vg_t;
typedef void __attribute__((address_space(3))) vl_t;

__device__ __forceinline__ void gld16(const void* g, void* l) {
  // async global->LDS, 16B per lane; LDS dest = wave-uniform base + lane*16
  __builtin_amdgcn_global_load_lds((vg_t*)g, (vl_t*)l, 16, 0, 0);
}

// ---------------------------------------------------------------------------
// Fused fp32->fp16 convert of x, Wq, Wk, Wv in ONE dispatch.
// ---------------------------------------------------------------------------
__global__ __launch_bounds__(256) void cvt_all(const float* __restrict__ x,
                                               const float* __restrict__ wq,
                                               const float* __restrict__ wk,
                                               const float* __restrict__ wv,
                                               f16* __restrict__ xb,
                                               f16* __restrict__ wh) {
  const int bx = blockIdx.x;
  const float* in; f16* out; int base;
  if (bx < 8192)       { in = x;  out = xb;             base = bx; }
  else if (bx < 9216)  { in = wq; out = wh;             base = bx - 8192; }
  else if (bx < 10240) { in = wk; out = wh + (1 << 20); base = bx - 9216; }
  else                 { in = wv; out = wh + (2 << 20); base = bx - 10240; }
  const long i = ((long)base * 256 + threadIdx.x) * 4;
  float4 v = *(const float4*)(in + i);
  f16x4 o = { (f16)v.x, (f16)v.y, (f16)v.z, (f16)v.w };
  *(f16x4*)(out + i) = o;
}

// ---------------------------------------------------------------------------
// 8-phase 256x256 QKV GEMM (T2+T3+T4+T5), BK=64, 512 thr / 8 waves (2M x 4N),
// LDS 128 KiB: buf{0,1} x {A,B} x [256][64] f16, chunk-XOR swizzled (T2).
// Schedule (per iteration j; t0=2j in buf0, t1=2j+1 in buf1):
//   ph1: read A0.q0 + B0.lo   | stage A1.h0<-t1      | MFMA q0 x Blo
//   ph2: read B0.hi           | stage A1.h1<-t1      | MFMA q0 x Bhi
//   ph3: read A0.q1           | stage B0.h0<-t0+2    | MFMA q1 x Bhi
//   ph4:                      | stage A0.h0<-t0+2    | MFMA q1 x Blo | vmcnt(4)
//   ph5: read A1.q0 + B1.lo   | stage B0.h1<-t0+2    | MFMA q0 x Blo
//   ph6: read B1.hi           | stage A0.h1<-t0+2    | MFMA q0 x Bhi
//   ph7: read A1.q1           | stage B1.h0<-t1+2    | MFMA q1 x Bhi
//   ph8:                      | stage B1.h1<-t1+2    | MFMA q1 x Blo | vmcnt(4)
// Ledger: every stage targets a half-tile whose LAST read ended >=1 barrier
// earlier (A halves free after ph3/ph7, B halves after ph2/ph6). vmcnt(4) at
// ph4/ph8 = 12 outstanding issues, oldest 8 = the next buffer's 4 half-tiles.
// Epilogue routes Q/K row-major, V transposed (same layout as before).
// ---------------------------------------------------------------------------
__global__ __launch_bounds__(512, 2) void qkv_8ph(const f16* __restrict__ A,
                                                  const f16* __restrict__ B,
                                                  f16* __restrict__ Qh) {
  __shared__ __align__(16) f16 ls[4][16384];  // buf0.A, buf0.B, buf1.A, buf1.B

  const int tid  = threadIdx.x;
  const int wave = tid >> 6;
  const int lane = tid & 63;
  const int fr   = lane & 15;
  const int fq   = lane >> 4;

  // XCD-chunked swizzle: 384 blocks, XCD x owns m-tiles [4x,4x+4) x all 12
  // n-tiles -> per-XCD A slice = 2 MB (L2-resident), B streams from LLC.
  const int lin = blockIdx.x;
  const int swz = (lin & 7) * 48 + (lin >> 3);
  const int m0  = (swz / 12) * 256;
  const int n0  = (swz % 12) * 256;

  const f16* Ab = A + (long)m0 * DIM;
  const f16* Bb = B + (long)n0 * DIM;

  const int wm = (wave & 1) * 128;   // wave's 128 rows of the 256-row tile
  const int wn = (wave >> 1) * 64;   // wave's 64 cols of the 256-col tile

  f16* lA0 = &ls[0][0]; f16* lB0 = &ls[1][0];
  f16* lA1 = &ls[2][0]; f16* lB1 = &ls[3][0];

  f32x4 acc[8][4] = {};
  f16x8 af[4][2], b0[2][2], b1[2][2];

  // stage one 128-row half-tile (2 x block-wide gld16 = 16 KiB); global chunk
  // pre-swizzled (sj ^ row&7) so linear LDS + swizzled ds_read match (rule 21)
#define STAGE(gb, lb, t, h)                                                    \
  {                                                                            \
    const int rr_ = tid >> 3, sj_ = tid & 7;                                   \
    _Pragma("unroll") for (int i_ = 0; i_ < 2; ++i_) {                         \
      const int row_ = (h) * 128 + i_ * 64 + rr_;                              \
      gld16(gb + (long)row_ * DIM + (t) * 64 + ((sj_ ^ (row_ & 7)) << 3),      \
            (void*)((lb) + (h) * 8192 + i_ * 4096 + tid * 8));                 \
    }                                                                          \
  }

#define LDA(lsrc, q)                                                           \
  {                                                                            \
    _Pragma("unroll") for (int mi_ = 0; mi_ < 4; ++mi_) {                      \
      const int row_ = wm + (q) * 64 + mi_ * 16 + fr;                          \
      _Pragma("unroll") for (int x_ = 0; x_ < 2; ++x_)                         \
        af[mi_][x_] = *(const f16x8*)((lsrc) + row_ * 64 +                     \
                                      (((x_ * 4 + fq) ^ (row_ & 7)) << 3));    \
    }                                                                          \
  }

#define LDB(lsrc, breg, s)                                                     \
  {                                                                            \
    _Pragma("unroll") for (int nj_ = 0; nj_ < 2; ++nj_) {                      \
      const int row_ = wn + (s) * 32 + nj_ * 16 + fr;                          \
      _Pragma("unroll") for (int x_ = 0; x_ < 2; ++x_)                         \
        breg[nj_][x_] = *(const f16x8*)((lsrc) + row_ * 64 +                   \
                                        (((x_ * 4 + fq) ^ (row_ & 7)) << 3));  \
    }                                                                          \
  }

#define MM(q, s, breg)                                                         \
  {                                                                            \
    __builtin_amdgcn_s_setprio(1);                                             \
    _Pragma("unroll") for (int mi_ = 0; mi_ < 4; ++mi_)                        \
    _Pragma("unroll") for (int nj_ = 0; nj_ < 2; ++nj_)                        \
    _Pragma("unroll") for (int x_ = 0; x_ < 2; ++x_)                           \
      acc[(q) * 4 + mi_][(s) * 2 + nj_] = __builtin_amdgcn_mfma_f32_16x16x32_f16( \
          af[mi_][x_], breg[nj_][x_], acc[(q) * 4 + mi_][(s) * 2 + nj_], 0, 0, 0); \
    __builtin_amdgcn_s_setprio(0);                                             \
  }

#define BAR() __builtin_amdgcn_s_barrier()
#define VMW(n) asm volatile("s_waitcnt vmcnt(" #n ")" ::: "memory")

  // prologue: buf0<-K0 (4 half-tiles), buf1.B<-K1 (2 half-tiles); oldest 8 of
  // 12 issues = all of K0 -> vmcnt(4)
  STAGE(Bb, lB0, 0, 0); STAGE(Ab, lA0, 0, 0);
  STAGE(Bb, lB0, 0, 1); STAGE(Ab, lA0, 0, 1);
  STAGE(Bb, lB1, 1, 0); STAGE(Bb, lB1, 1, 1);
  VMW(4);
  BAR();

  for (int j = 0; j < 8; ++j) {
    const int t0 = 2 * j;
    const bool nl = (j < 7);  // not-last: stop staging past K=1024

    // ph1
    LDA(lA0, 0); LDB(lB0, b0, 0);
    STAGE(Ab, lA1, t0 + 1, 0);
    BAR(); MM(0, 0, b0); BAR();
    // ph2
    LDB(lB0, b1, 1);
    STAGE(Ab, lA1, t0 + 1, 1);
    BAR(); MM(0, 1, b1); BAR();
    // ph3
    LDA(lA0, 1);
    if (nl) STAGE(Bb, lB0, t0 + 2, 0);
    BAR(); MM(1, 1, b1); BAR();
    // ph4
    if (nl) STAGE(Ab, lA0, t0 + 2, 0);
    BAR(); MM(1, 0, b0);
    if (nl) { VMW(4); } else { VMW(0); }  // buf1 (t1) fully landed
    BAR();
    // ph5
    LDA(lA1, 0); LDB(lB1, b0, 0);
    if (nl) STAGE(Bb, lB0, t0 + 2, 1);
    BAR(); MM(0, 0, b0); BAR();
    // ph6
    LDB(lB1, b1, 1);
    if (nl) STAGE(Ab, lA0, t0 + 2, 1);
    BAR(); MM(0, 1, b1); BAR();
    // ph7
    LDA(lA1, 1);
    if (nl) STAGE(Bb, lB1, t0 + 3, 0);
    BAR(); MM(1, 1, b1); BAR();
    // ph8
    if (nl) STAGE(Bb, lB1, t0 + 3, 1);
    BAR(); MM(1, 0, b0);
    if (nl) { VMW(4); BAR(); }  // buf0 (t0+2) fully landed
  }

#undef STAGE
#undef LDA
#undef LDB
#undef MM
#undef BAR
#undef VMW

  // Epilogue: n0 is block-uniform within one of {Q,K,V} (256 | 1024).
  f16* Kh = Qh + (size_t)8 * 1024 * 1024;
  f16* VT = Kh + (size_t)8 * 1024 * 1024;
#pragma unroll
  for (int mi = 0; mi < 8; ++mi) {
    const int row = m0 + wm + mi * 16 + fq * 4;
#pragma unroll
    for (int ni = 0; ni < 4; ++ni) {
      const int col = n0 + wn + ni * 16 + fr;
      if (n0 < 1024) {
#pragma unroll
        for (int r = 0; r < 4; ++r) Qh[(long)(row + r) * DIM + col] = (f16)acc[mi][ni][r];
      } else if (n0 < 2048) {
#pragma unroll
        for (int r = 0; r < 4; ++r) Kh[(long)(row + r) * DIM + (col - 1024)] = (f16)acc[mi][ni][r];
      } else {
        f16x4 o = { (f16)acc[mi][ni][0], (f16)acc[mi][ni][1],
                    (f16)acc[mi][ni][2], (f16)acc[mi][ni][3] };
        *(f16x4*)(VT + (long)(col - 2048) * (BATCH * SEQ) + row) = o;
      }
    }
  }
}

// ---------------------------------------------------------------------------
// NT GEMM: C[m,n] = sum_k A[m,k]*B[n,k], fp16 in, fp32 accumulate.
// 128x128 tile, 4 waves (2x2 of 64x64), 16x16x32 MFMA, BK template.
// MODE: 0 fp32 row-major, 1 fp16 row-major, 2 fp16 transposed.
// CAUSAL: 0 none, 1 skip tiles above diagonal (scores), 2 K-limit m0+128 (PV),
//         3 PV with balanced 1D grid (512 blocks): grid (16,8,4) round-robin
//         puts SAME-Keff pairs on one CU (b%16 == (b+256)%16) -> 1.88x makespan;
//         anti-symmetric longest<->shortest pairing makes per-CU Keff-sum const.
// BK=128 here: scores/PV grids are ~2 blocks/CU GRID-limited, so BK=64 buys no
// occupancy and doubles barrier drains (round-1 regression). BK=64 only pays
// when the grid is large enough to use 5 blocks/CU (m132 context).
// ---------------------------------------------------------------------------
template <int MODE, int CAUSAL, int BK>
__global__ __launch_bounds__(256) void gemm_bt(const f16* __restrict__ A, int lda, long aOffZ,
                                               const f16* __restrict__ B, int ldb, long bOffZ,
                                               void* __restrict__ Cv, int ldc, long cOffZ,
                                               int K) {
  constexpr int CH  = BK / 8;    // 16B chunks per row
  constexpr int RPL = 64 / CH;   // rows per wave-load
  constexpr int NL  = 32 / RPL;  // wave-loads per tile per wave
  __shared__ __align__(16) f16 lA[128 * BK];
  __shared__ __align__(16) f16 lB[128 * BK];

  const int tid  = threadIdx.x;
  const int wave = tid >> 6;
  const int lane = tid & 63;

  int m0, n0, z;
  if (CAUSAL == 3) {
    const int id   = blockIdx.x;
    const int item = (id < 256) ? id : 767 - id;
    const int mt   = 15 - (item >> 5);     // 32 blocks per Keff group
    const int j    = item & 31;
    m0 = mt * 128;
    n0 = (j & 7) * 128;
    z  = j >> 3;
  } else {
    m0 = blockIdx.x * 128;
    n0 = blockIdx.y * 128;
    z  = blockIdx.z;
  }

  if (CAUSAL == 1 && n0 >= m0 + 128) return;
  const int Keff = (CAUSAL >= 2) ? (m0 + 128) : K;

  const f16* Ab = A + (long)z * aOffZ + (long)m0 * lda;
  const f16* Bb = B + (long)z * bOffZ + (long)n0 * ldb;

  const int wm = (wave & 1) * 64;
  const int wn = (wave >> 1) * 64;

  f32x4 acc[4][4] = {};

  const int srow = lane / CH;
  const int sj   = lane % CH;
  const int fr   = lane & 15;
  const int fq   = lane >> 4;

  for (int kt = 0; kt < Keff; kt += BK) {
    __syncthreads();  // previous iteration's ds_reads done
#pragma unroll
    for (int j = 0; j < NL; ++j) {
      const int rgrp = j * 4 + wave;
      const int row  = rgrp * RPL + srow;
      const int gch  = sj ^ (row & (CH - 1));
      gld16(Ab + (long)row * lda + kt + gch * 8, (void*)(lA + rgrp * 512 + lane * 8));
      gld16(Bb + (long)row * ldb + kt + gch * 8, (void*)(lB + rgrp * 512 + lane * 8));
    }
    __syncthreads();  // vmcnt drained -> staging visible

#pragma unroll
    for (int kk = 0; kk < BK; kk += 32) {
      f16x8 af[4], bf[4];
#pragma unroll
      for (int i = 0; i < 4; ++i) {
        const int arow = wm + i * 16 + fr;
        const int ach  = (kk / 8 + fq) ^ (arow & (CH - 1));
        af[i] = *(const f16x8*)(lA + arow * BK + ach * 8);
        const int brow = wn + i * 16 + fr;
        const int bch  = (kk / 8 + fq) ^ (brow & (CH - 1));
        bf[i] = *(const f16x8*)(lB + brow * BK + bch * 8);
      }
#pragma unroll
      for (int mi = 0; mi < 4; ++mi)
#pragma unroll
        for (int ni = 0; ni < 4; ++ni)
          acc[mi][ni] = __builtin_amdgcn_mfma_f32_16x16x32_f16(af[mi], bf[ni], acc[mi][ni], 0, 0, 0);
    }
  }

  // Epilogue. C/D layout: col = lane&15, row = (lane>>4)*4 + reg
#pragma unroll
  for (int mi = 0; mi < 4; ++mi) {
    const int row = m0 + wm + mi * 16 + fq * 4;
#pragma unroll
    for (int ni = 0; ni < 4; ++ni) {
      const int col = n0 + wn + ni * 16 + fr;
      if constexpr (MODE == 0) {
        float* C = (float*)Cv + (long)z * cOffZ;
#pragma unroll
        for (int r = 0; r < 4; ++r) C[(long)(row + r) * ldc + col] = acc[mi][ni][r];
      } else if constexpr (MODE == 1) {
        f16* C = (f16*)Cv + (long)z * cOffZ;
#pragma unroll
        for (int r = 0; r < 4; ++r) C[(long)(row + r) * ldc + col] = (f16)acc[mi][ni][r];
      } else {  // MODE 2
        f16* C = (f16*)Cv + (long)z * cOffZ;
        f16x4 o = { (f16)acc[mi][ni][0], (f16)acc[mi][ni][1],
                    (f16)acc[mi][ni][2], (f16)acc[mi][ni][3] };
        *(f16x4*)(C + (long)col * ldc + row) = o;
      }
    }
  }
}

// ---------------------------------------------------------------------------
// Causal softmax over f16 score rows, in-place (zero above diagonal).
// grid = (SEQ, BATCH), block = 256, 8 contiguous elems/thread (f16x8).
// Threads entirely above the diagonal skip the load; writes stay full.
// ---------------------------------------------------------------------------
__global__ __launch_bounds__(256) void softmax_causal(f16* S) {
  const int q = blockIdx.x, b = blockIdx.y;
  f16* row = S + ((long)b * SEQ + q) * SEQ;
  const int tid = threadIdx.x;
  const int lane = tid & 63, wave = tid >> 6;
  const int nvalid = q + 1;

  f16x8 vv = {};
  if (tid * 8 < nvalid) vv = *(const f16x8*)(row + tid * 8);
  float v[8];
  float m = -3.0e38f;
#pragma unroll
  for (int i = 0; i < 8; ++i) {
    const int k = tid * 8 + i;
    v[i] = (k < nvalid) ? (float)vv[i] * 0.03125f : -3.0e38f;
    m = fmaxf(m, v[i]);
  }
#pragma unroll
  for (int off = 32; off; off >>= 1) m = fmaxf(m, __shfl_xor(m, off));
  __shared__ float redm[4], reds[4];
  if (lane == 0) redm[wave] = m;
  __syncthreads();
  m = fmaxf(fmaxf(redm[0], redm[1]), fmaxf(redm[2], redm[3]));

  float s = 0.f;
#pragma unroll
  for (int i = 0; i < 8; ++i) {
    const float p = (v[i] > -1.0e37f) ? __expf(v[i] - m) : 0.f;
    v[i] = p;
    s += p;
  }
#pragma unroll
  for (int off = 32; off; off >>= 1) s += __shfl_xor(s, off);
  if (lane == 0) reds[wave] = s;
  __syncthreads();
  s = reds[0] + reds[1] + reds[2] + reds[3];
  const float inv = 1.f / s;
  f16x8 o;
#pragma unroll
  for (int i = 0; i < 8; ++i) o[i] = (f16)(v[i] * inv);
  *(f16x8*)(row + tid * 8) = o;
}

// ---------------------------------------------------------------------------
extern "C" void kernel_launch(void* const* d_in, const int* in_sizes, int n_in,
                              void* d_out, int out_size, void* d_ws, size_t ws_size,
                              hipStream_t stream) {
  const float* x  = (const float*)d_in[0];
  const float* Wq = (const float*)d_in[1];
  const float* Wk = (const float*)d_in[2];
  const float* Wv = (const float*)d_in[3];
  float* out = (float*)d_out;

  // ws layout (f16 elems): xb 8M | Wh 3M | Qh 8M | Kh 8M | VT 8M ([1024][8192]) |
  //                        Sc 16M f16 scores->probs in place (4 x 2048 x 2048)
  if (ws_size < (size_t)51 * 1024 * 1024 * 2) return;

  f16* xb = (f16*)d_ws;
  f16* Wh = xb + (size_t)8 * 1024 * 1024;
  f16* Qh = Wh + (size_t)3 * 1024 * 1024;
  f16* Kh = Qh + (size_t)8 * 1024 * 1024;
  f16* VT = Kh + (size_t)8 * 1024 * 1024;
  f16* Sc = VT + (size_t)8 * 1024 * 1024;

  const long QOFF = (long)SEQ * DIM;  // per-batch Q/K offset
  const long SOFF = (long)SEQ * SEQ;  // per-batch score offset (f16 elems)

  cvt_all<<<11264, 256, 0, stream>>>(x, Wq, Wk, Wv, xb, Wh);

  // Fused QKV: M=8192, N=3072 (Wq|Wk|Wv in Wh), K=1024 -- 8-phase 256x256.
  qkv_8ph<<<384, 512, 0, stream>>>(xb, Wh, Qh);

  // scores = Q K^T (causal block-skip), f16 out, BK=128 (grid-limited occupancy)
  gemm_bt<1, 1, 128><<<dim3(16, 16, 4), 256, 0, stream>>>(Qh, DIM, QOFF, Kh, DIM, QOFF,
                                                          Sc, SEQ, SOFF, DIM);

  // causal softmax (scale 1/32), in-place f16 probs, zero above diagonal
  softmax_causal<<<dim3(SEQ, BATCH), 256, 0, stream>>>(Sc);

  // Z = P V  (A = probs f16 ld 2048; B = VT ld 8192; per-M-tile K-limit),
  // BK=128 + balanced 1D grid (longest<->shortest pairing kills the Keff tail)
  gemm_bt<0, 3, 128><<<dim3(512, 1, 1), 256, 0, stream>>>(Sc, SEQ, SOFF,
                                                          VT, BATCH * SEQ, SEQ,
                                                          out, DIM, (long)SEQ * DIM, SEQ);
}